// Round 7
// baseline (346.437 us; speedup 1.0000x reference)
//
#include <hip/hip_runtime.h>

typedef __attribute__((ext_vector_type(8))) short bf16x8;
typedef __attribute__((ext_vector_type(4))) float f32x4;

__device__ __forceinline__ unsigned short f2bf(float f) {  // RNE
  unsigned u = __float_as_uint(f);
  u += 0x7FFFu + ((u >> 16) & 1u);
  return (unsigned short)(u >> 16);
}
__device__ __forceinline__ float bflo(unsigned u) { return __uint_as_float(u << 16); }
__device__ __forceinline__ float bfhi(unsigned u) { return __uint_as_float(u & 0xFFFF0000u); }
__device__ __forceinline__ float bf1(unsigned short h) { return __uint_as_float(((unsigned)h) << 16); }

// ---------------- MFMA bf16 GEMM body (m89/m91-verified layouts) ----------------
// A: m=lane&15, k=quad*8+j   B: n=lane&15, k=quad*8+j   D: col=lane&15, row=quad*4+reg
template <int CO, bool AF32>
__device__ __forceinline__ void gemm_body(const void* __restrict__ Aptr,
                                          const float* __restrict__ W,
                                          unsigned short* __restrict__ Y, int N,
                                          int bid, int tid, unsigned short* Wl) {
  constexpr int K = 128;
  constexpr int SP = K + 8;  // padded LDS row stride (shorts)
  for (int i = tid; i < K * CO; i += 256) {
    int k = i / CO, n = i % CO;
    Wl[n * SP + k] = f2bf(W[i]);
  }
  __syncthreads();

  const int lane = tid & 63;
  const int quad = lane >> 4, l16 = lane & 15;
  const int mbase = bid * 64 + (tid >> 6) * 16;
  const int arow = min(mbase + l16, N - 1);

  bf16x8 afrag[4];
  if constexpr (AF32) {
    const float* A = (const float*)Aptr + (size_t)arow * K;
#pragma unroll
    for (int ks = 0; ks < 4; ks++) {
      const float4* p = (const float4*)(A + ks * 32 + quad * 8);
      float4 f0 = p[0], f1 = p[1];
      afrag[ks] = (bf16x8){(short)f2bf(f0.x), (short)f2bf(f0.y), (short)f2bf(f0.z), (short)f2bf(f0.w),
                           (short)f2bf(f1.x), (short)f2bf(f1.y), (short)f2bf(f1.z), (short)f2bf(f1.w)};
    }
  } else {
    const unsigned short* A = (const unsigned short*)Aptr + (size_t)arow * K;
#pragma unroll
    for (int ks = 0; ks < 4; ks++) afrag[ks] = *(const bf16x8*)(A + ks * 32 + quad * 8);
  }

#pragma unroll
  for (int ct = 0; ct < CO / 16; ct++) {
    f32x4 acc = {0.0f, 0.0f, 0.0f, 0.0f};
#pragma unroll
    for (int ks = 0; ks < 4; ks++) {
      bf16x8 b = *(const bf16x8*)(&Wl[(ct * 16 + l16) * SP + ks * 32 + quad * 8]);
      acc = __builtin_amdgcn_mfma_f32_16x16x32_bf16(afrag[ks], b, acc, 0, 0, 0);
    }
#pragma unroll
    for (int reg = 0; reg < 4; reg++) {
      int node = mbase + quad * 4 + reg;
      if (node < N) Y[(size_t)node * CO + ct * 16 + l16] = f2bf(acc[reg]);
    }
  }
}

// ---------------- mega1: GEMM1 | edge histogram | batch boundaries (independent) ----
__global__ __launch_bounds__(256) void k_mega1(const float* __restrict__ x,
                                               const float* __restrict__ W1,
                                               unsigned short* __restrict__ xw1b, int N,
                                               const int* __restrict__ dst,
                                               int* __restrict__ cnt, int E,
                                               const int* __restrict__ batch,
                                               int* __restrict__ firstIdx,
                                               int gM, int gE) {
  __shared__ unsigned short Wl[128 * 136];
  const int bid = blockIdx.x, tid = threadIdx.x;
  if (bid < gM) {
    gemm_body<128, true>(x, W1, xw1b, N, bid, tid, Wl);
  } else if (bid < gM + gE) {
    int e = (bid - gM) * 256 + tid;
    if (e < E) atomicAdd(&cnt[dst[e]], 1);
  } else {
    int n = (bid - gM - gE) * 256 + tid;
    if (n < N) {
      int b = batch[n];
      if (n == 0 || batch[n - 1] != b) firstIdx[b] = n + 1;  // first occurrence, +1-encoded
    }
  }
}

// ---------------- segment allocation (order-free) + c self-loop term ----------------
__global__ void k_seg(const int* __restrict__ cnt, int* __restrict__ start,
                      int* __restrict__ cursor, float* __restrict__ dinv,
                      int* __restrict__ counter, const int* __restrict__ batch,
                      float* __restrict__ c, int N) {
  const int v = blockIdx.x * 256 + threadIdx.x;
  const int lane = threadIdx.x & 63;
  int cn = (v < N) ? cnt[v] : 0;
  int incl = cn;
#pragma unroll
  for (int d = 1; d < 64; d <<= 1) {
    int t = __shfl_up(incl, d, 64);
    if (lane >= d) incl += t;
  }
  int base = 0;
  if (lane == 63) base = atomicAdd(counter, incl);
  base = __shfl(base, 63, 64);
  if (v < N) {
    int s = base + incl - cn;
    start[v] = s;
    cursor[v] = s;
    float dv = rsqrtf((float)(cn + 1));  // +1 self-loop
    dinv[v] = dv;
    c[((size_t)v << 6) + batch[v]] = dv * dv;  // c zeroed; sole writer before k_fill
  }
}

// fill packed (src, weight) pairs for layer 1 AND accumulate pool-coefficients c
__global__ void k_fill(const int* __restrict__ src, const int* __restrict__ dst,
                       const int* __restrict__ batch, const float* __restrict__ dinv,
                       int* __restrict__ cursor, int2* __restrict__ colw,
                       float* __restrict__ c, int E) {
  int e = blockIdx.x * 256 + threadIdx.x;
  if (e < E) {
    int s = src[e], d = dst[e];
    float w = dinv[s] * dinv[d];
    int p = atomicAdd(&cursor[d], 1);
    colw[p] = make_int2(s, __float_as_int(w));
    atomicAdd(&c[((size_t)s << 6) + batch[d]], w);
  }
}

// ---------------- layer-1 aggregate: lane-prefetched edges, bf16 rows ----------------
__global__ __launch_bounds__(256) void k_agg128(const unsigned short* __restrict__ xwb,
                                                const float* __restrict__ dinv,
                                                const int* __restrict__ start,
                                                const int* __restrict__ cnt,
                                                const int2* __restrict__ colw,
                                                const float* __restrict__ bias,
                                                unsigned short* __restrict__ out, int N) {
  const int lane = threadIdx.x & 63;
  const int v = blockIdx.x * 4 + (threadIdx.x >> 6);
  if (v >= N) return;
  const float dv = dinv[v];
  unsigned u = ((const unsigned*)(xwb + (size_t)v * 128))[lane];
  float ax = dv * dv * bflo(u);
  float ay = dv * dv * bfhi(u);
  const int j0 = start[v], jc = cnt[v];
  for (int base = 0; base < jc; base += 64) {
    int2 cw = (base + lane < jc) ? colw[j0 + base + lane] : make_int2(0, 0);
    const int m = min(64, jc - base);
#pragma unroll 4
    for (int t = 0; t < m; t++) {
      int s = __shfl(cw.x, t, 64);
      float w = __int_as_float(__shfl(cw.y, t, 64));
      unsigned r = ((const unsigned*)(xwb + (size_t)s * 128))[lane];
      ax += w * bflo(r);
      ay += w * bfhi(r);
    }
  }
  float2 b = ((const float2*)bias)[lane];
  ax = fmaxf(ax + b.x, 0.0f);
  ay = fmaxf(ay + b.y, 0.0f);
  ((unsigned*)(out + (size_t)v * 128))[lane] =
      (unsigned)f2bf(ax) | ((unsigned)f2bf(ay) << 16);
}

// ---------------- pooled[f][g] = sum_s c[s][g] * h1[s][f]  (dense, coalesced) --------
// thread (g2 = tid&31 -> handles g2, g2+32; fg = tid>>5 -> 16 features)
__global__ __launch_bounds__(256) void k_cpool(const float* __restrict__ c,
                                               const unsigned short* __restrict__ h1b,
                                               float* __restrict__ pooled, int N) {
  __shared__ float cs[64 * 64];    // 16 KB
  __shared__ float hs[64 * 128];   // 32 KB
  const int tid = threadIdx.x;
  const int g2 = tid & 31;
  const int fg = tid >> 5;
  const int npb = (N + gridDim.x - 1) / gridDim.x;
  const int base = blockIdx.x * npb;
  const int kend = min(base + npb, N);
  float accA[16], accB[16];
#pragma unroll
  for (int i = 0; i < 16; i++) { accA[i] = 0.f; accB[i] = 0.f; }

  for (int k0 = base; k0 < kend; k0 += 64) {
    for (int i = tid; i < 64 * 64; i += 256) {
      int n = k0 + (i >> 6);
      cs[i] = (n < kend) ? c[((size_t)k0 << 6) + i] : 0.0f;
    }
    for (int i = tid; i < 64 * 128; i += 256) {
      int n = min(k0 + (i >> 7), N - 1);
      hs[i] = bf1(h1b[(size_t)n * 128 + (i & 127)]);
    }
    __syncthreads();
    const int kmax = min(64, kend - k0);
    for (int kk = 0; kk < kmax; kk++) {
      float wA = cs[kk * 64 + g2];
      float wB = cs[kk * 64 + g2 + 32];
      const float4* hp = (const float4*)&hs[kk * 128 + fg * 16];
#pragma unroll
      for (int uu = 0; uu < 4; uu++) {
        float4 hv = hp[uu];
        accA[uu * 4 + 0] += wA * hv.x; accA[uu * 4 + 1] += wA * hv.y;
        accA[uu * 4 + 2] += wA * hv.z; accA[uu * 4 + 3] += wA * hv.w;
        accB[uu * 4 + 0] += wB * hv.x; accB[uu * 4 + 1] += wB * hv.y;
        accB[uu * 4 + 2] += wB * hv.z; accB[uu * 4 + 3] += wB * hv.w;
      }
    }
    __syncthreads();
  }
#pragma unroll
  for (int i = 0; i < 16; i++) {
    int f = fg * 16 + i;
    atomicAdd(&pooled[f * 64 + g2], accA[i]);
    atomicAdd(&pooled[f * 64 + g2 + 32], accB[i]);
  }
}

// ---------------- final: counts, (pooled/n) @ W2 + b2 -> out ----------------
__global__ void k_final(const float* __restrict__ pooled, const int* __restrict__ firstIdx,
                        const float* __restrict__ W2, const float* __restrict__ b2,
                        float* __restrict__ out, int N) {
  __shared__ float rinv[64];
  const int tid = threadIdx.x;
  if (tid < 64) {
    int raw = firstIdx[tid];
    int fi = (raw > 0) ? raw - 1 : 0x7FFFFFFF;
    int m = fi;
#pragma unroll
    for (int d = 1; d < 64; d <<= 1) {
      int t = __shfl_down(m, d, 64);
      if (tid + d < 64) m = min(m, t);
    }
    int nxtm = __shfl_down(m, 1, 64);           // min first-idx over graphs > tid
    int nxt = (tid == 63) ? N : min(nxtm, N);
    int cgt = (fi == 0x7FFFFFFF) ? 0 : (nxt - fi);
    rinv[tid] = 1.0f / fmaxf((float)cgt, 1.0f);
  }
  __syncthreads();
  const int g = tid & 63;
  const int jg = tid >> 6;  // 4 groups of 16 outputs
  float acc[16];
#pragma unroll
  for (int i = 0; i < 16; i++) acc[i] = 0.f;
  for (int f = 0; f < 128; f++) {
    float p = pooled[f * 64 + g];
#pragma unroll
    for (int i = 0; i < 16; i++) acc[i] += p * W2[f * 64 + jg * 16 + i];
  }
  float r = rinv[g];
#pragma unroll
  for (int i = 0; i < 16; i++)
    out[g * 64 + jg * 16 + i] = r * acc[i] + b2[jg * 16 + i];
}

// ---------------- launch ----------------

extern "C" void kernel_launch(void* const* d_in, const int* in_sizes, int n_in,
                              void* d_out, int out_size, void* d_ws, size_t ws_size,
                              hipStream_t stream) {
  const float* x     = (const float*)d_in[0];
  const int*   ei    = (const int*)d_in[1];
  const int*   batch = (const int*)d_in[2];
  const float* W1    = (const float*)d_in[3];
  const float* b1    = (const float*)d_in[4];
  const float* W2    = (const float*)d_in[5];
  const float* b2    = (const float*)d_in[6];

  const int N = in_sizes[2];       // 50000
  const int E = in_sizes[1] / 2;   // 800000
  const int* src  = ei;
  const int* dstv = ei + E;

  // workspace layout
  unsigned short* xw1b = (unsigned short*)d_ws;      // N*128 bf16
  unsigned short* h1b  = xw1b + (size_t)N * 128;     // N*128 bf16
  // zero region: cnt[N] counter[1] firstIdx[64] pooled[8192] c[N*64]
  int*   cnt      = (int*)(h1b + (size_t)N * 128);
  int*   counter  = cnt + N;
  int*   firstIdx = counter + 1;
  float* pooled   = (float*)(firstIdx + 64);         // 128*64, f-major
  float* c        = pooled + 128 * 64;               // N*64
  const size_t zero_ints = (size_t)N + 1 + 64 + 128 * 64 + (size_t)N * 64;
  // non-zeroed scratch
  int*   startv   = (int*)(c + (size_t)N * 64);      // N
  int*   cursor   = startv + N;                      // N
  float* dinv     = (float*)(cursor + N);            // N
  uintptr_t cw    = ((uintptr_t)(dinv + N) + 7) & ~(uintptr_t)7;
  int2*  colw     = (int2*)cw;                       // E pairs
  float* outp     = (float*)d_out;                   // 64*64

  hipMemsetAsync(cnt, 0, zero_ints * sizeof(int), stream);

  const int gM = (N + 63) / 64;     // 782
  const int gE = (E + 255) / 256;   // 3125
  const int gN = (N + 255) / 256;   // 196
  const int gA = (N + 3) / 4;       // 12500

  // GEMM1 + histogram + batch boundaries in one launch (independent work)
  k_mega1<<<gM + gE + gN, 256, 0, stream>>>(x, W1, xw1b, N, dstv, cnt, E,
                                            batch, firstIdx, gM, gE);
  k_seg<<<gN, 256, 0, stream>>>(cnt, startv, cursor, dinv, counter, batch, c, N);
  k_fill<<<gE, 256, 0, stream>>>(src, dstv, batch, dinv, cursor, colw, c, E);

  // layer 1 aggregate (+bias+relu)
  k_agg128<<<gA, 256, 0, stream>>>(xw1b, dinv, startv, cnt, colw, b1, h1b, N);

  // layer 2 + pool, commuted: pooled = h1^T c, then (pooled/n) @ W2 + b2
  k_cpool<<<512, 256, 0, stream>>>(c, h1b, pooled, N);
  k_final<<<1, 256, 0, stream>>>(pooled, firstIdx, W2, b2, outp, N);
}

// Round 8
// 345.631 us; speedup vs baseline: 1.0023x; 1.0023x over previous
//
#include <hip/hip_runtime.h>

typedef __attribute__((ext_vector_type(8))) short bf16x8;
typedef __attribute__((ext_vector_type(4))) float f32x4;

__device__ __forceinline__ unsigned short f2bf(float f) {  // RNE
  unsigned u = __float_as_uint(f);
  u += 0x7FFFu + ((u >> 16) & 1u);
  return (unsigned short)(u >> 16);
}
__device__ __forceinline__ float bflo(unsigned u) { return __uint_as_float(u << 16); }
__device__ __forceinline__ float bfhi(unsigned u) { return __uint_as_float(u & 0xFFFF0000u); }

// ---------------- MFMA bf16 GEMM body (m89/m91-verified layouts) ----------------
// A: m=lane&15, k=quad*8+j   B: n=lane&15, k=quad*8+j   D: col=lane&15, row=quad*4+reg
__device__ __forceinline__ void gemm1_body(const float* __restrict__ A0,
                                           const float* __restrict__ W,
                                           unsigned short* __restrict__ Y, int N,
                                           int bid, int tid, unsigned short* Wl) {
  constexpr int K = 128, CO = 128;
  constexpr int SP = K + 8;
  for (int i = tid; i < K * CO; i += 256) {
    int k = i / CO, n = i % CO;
    Wl[n * SP + k] = f2bf(W[i]);
  }
  __syncthreads();

  const int lane = tid & 63;
  const int quad = lane >> 4, l16 = lane & 15;
  const int mbase = bid * 64 + (tid >> 6) * 16;
  const int arow = min(mbase + l16, N - 1);

  bf16x8 afrag[4];
  const float* A = A0 + (size_t)arow * K;
#pragma unroll
  for (int ks = 0; ks < 4; ks++) {
    const float4* p = (const float4*)(A + ks * 32 + quad * 8);
    float4 f0 = p[0], f1 = p[1];
    afrag[ks] = (bf16x8){(short)f2bf(f0.x), (short)f2bf(f0.y), (short)f2bf(f0.z), (short)f2bf(f0.w),
                         (short)f2bf(f1.x), (short)f2bf(f1.y), (short)f2bf(f1.z), (short)f2bf(f1.w)};
  }

#pragma unroll
  for (int ct = 0; ct < CO / 16; ct++) {
    f32x4 acc = {0.0f, 0.0f, 0.0f, 0.0f};
#pragma unroll
    for (int ks = 0; ks < 4; ks++) {
      bf16x8 b = *(const bf16x8*)(&Wl[(ct * 16 + l16) * SP + ks * 32 + quad * 8]);
      acc = __builtin_amdgcn_mfma_f32_16x16x32_bf16(afrag[ks], b, acc, 0, 0, 0);
    }
#pragma unroll
    for (int reg = 0; reg < 4; reg++) {
      int node = mbase + quad * 4 + reg;
      if (node < N) Y[(size_t)node * CO + ct * 16 + l16] = f2bf(acc[reg]);
    }
  }
}

// ---------------- mega1: GEMM1 | edge histogram | batch boundaries (independent) ----
__global__ __launch_bounds__(256) void k_mega1(const float* __restrict__ x,
                                               const float* __restrict__ W1,
                                               unsigned short* __restrict__ xw1b, int N,
                                               const int* __restrict__ dst,
                                               int* __restrict__ cnt, int E,
                                               const int* __restrict__ batch,
                                               int* __restrict__ firstIdx,
                                               int gM, int gE) {
  __shared__ unsigned short Wl[128 * 136];
  const int bid = blockIdx.x, tid = threadIdx.x;
  if (bid < gM) {
    gemm1_body(x, W1, xw1b, N, bid, tid, Wl);
  } else if (bid < gM + gE) {
    int e = (bid - gM) * 256 + tid;
    if (e < E) atomicAdd(&cnt[dst[e]], 1);
  } else {
    int n = (bid - gM - gE) * 256 + tid;
    if (n < N) {
      int b = batch[n];
      if (n == 0 || batch[n - 1] != b) firstIdx[b] = n + 1;  // first occurrence, +1-encoded
    }
  }
}

// ---------------- segment allocation (order-free) ----------------
__global__ void k_seg(const int* __restrict__ cnt, int* __restrict__ start,
                      int* __restrict__ cursor, float* __restrict__ dinv,
                      int* __restrict__ counter, int N) {
  const int v = blockIdx.x * 256 + threadIdx.x;
  const int lane = threadIdx.x & 63;
  int cn = (v < N) ? cnt[v] : 0;
  int incl = cn;
#pragma unroll
  for (int d = 1; d < 64; d <<= 1) {
    int t = __shfl_up(incl, d, 64);
    if (lane >= d) incl += t;
  }
  int base = 0;
  if (lane == 63) base = atomicAdd(counter, incl);
  base = __shfl(base, 63, 64);
  if (v < N) {
    int s = base + incl - cn;
    start[v] = s;
    cursor[v] = s;
    dinv[v] = rsqrtf((float)(cn + 1));  // +1 self-loop
  }
}

// fill packed (src, weight) pairs, grouped by dst; grid-stride for chain overlap
__global__ __launch_bounds__(256) void k_fill(const int* __restrict__ src,
                                              const int* __restrict__ dst,
                                              const float* __restrict__ dinv,
                                              int* __restrict__ cursor,
                                              int2* __restrict__ colw, int E) {
  const int stride = gridDim.x * 256;
  for (int e = blockIdx.x * 256 + threadIdx.x; e < E; e += stride) {
    int s = src[e], d = dst[e];
    float w = dinv[s] * dinv[d];
    int p = atomicAdd(&cursor[d], 1);
    colw[p] = make_int2(s, __float_as_int(w));
  }
}

// ---------------- layer-1 aggregate: lane-prefetched edges, bf16 rows ----------------
__global__ __launch_bounds__(256) void k_agg128(const unsigned short* __restrict__ xwb,
                                                const float* __restrict__ dinv,
                                                const int* __restrict__ start,
                                                const int* __restrict__ cnt,
                                                const int2* __restrict__ colw,
                                                const float* __restrict__ bias,
                                                unsigned short* __restrict__ out, int N) {
  const int lane = threadIdx.x & 63;
  const int v = blockIdx.x * 4 + (threadIdx.x >> 6);
  if (v >= N) return;
  const float dv = dinv[v];
  unsigned u = ((const unsigned*)(xwb + (size_t)v * 128))[lane];
  float ax = dv * dv * bflo(u);
  float ay = dv * dv * bfhi(u);
  const int j0 = start[v], jc = cnt[v];
  for (int base = 0; base < jc; base += 64) {
    int2 cw = (base + lane < jc) ? colw[j0 + base + lane] : make_int2(0, 0);
    const int m = min(64, jc - base);
#pragma unroll 4
    for (int t = 0; t < m; t++) {
      int s = __shfl(cw.x, t, 64);
      float w = __int_as_float(__shfl(cw.y, t, 64));
      unsigned r = ((const unsigned*)(xwb + (size_t)s * 128))[lane];
      ax += w * bflo(r);
      ay += w * bfhi(r);
    }
  }
  float2 b = ((const float2*)bias)[lane];
  ax = fmaxf(ax + b.x, 0.0f);
  ay = fmaxf(ay + b.y, 0.0f);
  ((unsigned*)(out + (size_t)v * 128))[lane] =
      (unsigned)f2bf(ax) | ((unsigned)f2bf(ay) << 16);
}

// ---------------- second aggregate on h1 (128-dim) fused with pooling ----------------
// pool(Agg(h1 W2)) = pool(Agg(h1)) W2: accumulate Agg(h1)[v] into stage[batch[v]].
__global__ __launch_bounds__(256) void k_aggpool128(const unsigned short* __restrict__ h1b,
                                                    const float* __restrict__ dinv,
                                                    const int* __restrict__ start,
                                                    const int* __restrict__ cnt,
                                                    const int2* __restrict__ colw,
                                                    const int* __restrict__ batch,
                                                    float* __restrict__ stage, int N) {
  __shared__ float2 red[256];
  const int lane = threadIdx.x & 63;
  const int wv = threadIdx.x >> 6;
  const int v = blockIdx.x * 4 + wv;
  float ax = 0.0f, ay = 0.0f;
  if (v < N) {
    const float dv = dinv[v];
    unsigned u = ((const unsigned*)(h1b + (size_t)v * 128))[lane];
    ax = dv * dv * bflo(u);
    ay = dv * dv * bfhi(u);
    const int j0 = start[v], jc = cnt[v];
    for (int base = 0; base < jc; base += 64) {
      int2 cw = (base + lane < jc) ? colw[j0 + base + lane] : make_int2(0, 0);
      const int m = min(64, jc - base);
#pragma unroll 4
      for (int t = 0; t < m; t++) {
        int s = __shfl(cw.x, t, 64);
        float w = __int_as_float(__shfl(cw.y, t, 64));
        unsigned r = ((const unsigned*)(h1b + (size_t)s * 128))[lane];
        ax += w * bflo(r);
        ay += w * bfhi(r);
      }
    }
  }
  red[threadIdx.x] = make_float2(ax, ay);
  __syncthreads();
  const int v0 = blockIdx.x * 4;
  const int b0 = batch[min(v0, N - 1)];
  const int b3 = batch[min(v0 + 3, N - 1)];
  if ((b0 == b3) && (v0 + 3 < N)) {          // sorted batch -> block-uniform graph
    if (wv == 0) {
      float2 r0 = red[lane], r1 = red[64 + lane], r2 = red[128 + lane], r3 = red[192 + lane];
      atomicAdd(&stage[b0 * 128 + 2 * lane], r0.x + r1.x + r2.x + r3.x);
      atomicAdd(&stage[b0 * 128 + 2 * lane + 1], r0.y + r1.y + r2.y + r3.y);
    }
  } else if (v < N) {
    int b = batch[v];
    atomicAdd(&stage[b * 128 + 2 * lane], ax);
    atomicAdd(&stage[b * 128 + 2 * lane + 1], ay);
  }
}

// ---------------- final: counts; out = (stage/n) @ W2 + b2 ----------------
__global__ void k_final(const float* __restrict__ stage, const int* __restrict__ firstIdx,
                        const float* __restrict__ W2, const float* __restrict__ b2,
                        float* __restrict__ out, int N) {
  __shared__ float rinv[64];
  const int tid = threadIdx.x;
  if (tid < 64) {
    int raw = firstIdx[tid];
    int fi = (raw > 0) ? raw - 1 : 0x7FFFFFFF;
    int m = fi;
#pragma unroll
    for (int d = 1; d < 64; d <<= 1) {
      int t = __shfl_down(m, d, 64);
      if (tid + d < 64) m = min(m, t);
    }
    int nxtm = __shfl_down(m, 1, 64);           // min first-idx over graphs > tid
    int nxt = (tid == 63) ? N : min(nxtm, N);
    int cgt = (fi == 0x7FFFFFFF) ? 0 : (nxt - fi);
    rinv[tid] = 1.0f / fmaxf((float)cgt, 1.0f);
  }
  __syncthreads();
  const int g = tid >> 2;        // 64 graphs
  const int jg = tid & 3;        // 4 groups of 16 outputs
  float acc[16];
#pragma unroll
  for (int i = 0; i < 16; i++) acc[i] = 0.f;
  for (int f = 0; f < 128; f++) {
    float p = stage[g * 128 + f];
#pragma unroll
    for (int i = 0; i < 16; i++) acc[i] += p * W2[f * 64 + jg * 16 + i];
  }
  float r = rinv[g];
#pragma unroll
  for (int i = 0; i < 16; i++)
    out[g * 64 + jg * 16 + i] = r * acc[i] + b2[jg * 16 + i];
}

// ---------------- launch ----------------

extern "C" void kernel_launch(void* const* d_in, const int* in_sizes, int n_in,
                              void* d_out, int out_size, void* d_ws, size_t ws_size,
                              hipStream_t stream) {
  const float* x     = (const float*)d_in[0];
  const int*   ei    = (const int*)d_in[1];
  const int*   batch = (const int*)d_in[2];
  const float* W1    = (const float*)d_in[3];
  const float* b1    = (const float*)d_in[4];
  const float* W2    = (const float*)d_in[5];
  const float* b2    = (const float*)d_in[6];

  const int N = in_sizes[2];       // 50000
  const int E = in_sizes[1] / 2;   // 800000
  const int* src  = ei;
  const int* dstv = ei + E;

  // workspace layout
  unsigned short* xw1b = (unsigned short*)d_ws;      // N*128 bf16
  unsigned short* h1b  = xw1b + (size_t)N * 128;     // N*128 bf16
  // zero region: cnt[N] counter[1] firstIdx[64] stage[64*128]
  int*   cnt      = (int*)(h1b + (size_t)N * 128);
  int*   counter  = cnt + N;
  int*   firstIdx = counter + 1;
  float* stage    = (float*)(firstIdx + 64);         // 64*128 f32
  const size_t zero_ints = (size_t)N + 1 + 64 + 64 * 128;
  // non-zeroed scratch
  int*   startv   = (int*)(stage + 64 * 128);        // N
  int*   cursor   = startv + N;                      // N
  float* dinv     = (float*)(cursor + N);            // N
  uintptr_t cw    = ((uintptr_t)(dinv + N) + 7) & ~(uintptr_t)7;
  int2*  colw     = (int2*)cw;                       // E pairs
  float* outp     = (float*)d_out;                   // 64*64

  hipMemsetAsync(cnt, 0, zero_ints * sizeof(int), stream);

  const int gM = (N + 63) / 64;     // 782
  const int gE = (E + 255) / 256;   // 3125
  const int gN = (N + 255) / 256;   // 196
  const int gA = (N + 3) / 4;       // 12500

  // GEMM1 + histogram + batch boundaries in one launch (independent work)
  k_mega1<<<gM + gE + gN, 256, 0, stream>>>(x, W1, xw1b, N, dstv, cnt, E,
                                            batch, firstIdx, gM, gE);
  k_seg<<<gN, 256, 0, stream>>>(cnt, startv, cursor, dinv, counter, N);
  k_fill<<<1024, 256, 0, stream>>>(src, dstv, dinv, cursor, colw, E);

  // layer 1 aggregate (+bias+relu)
  k_agg128<<<gA, 256, 0, stream>>>(xw1b, dinv, startv, cnt, colw, b1, h1b, N);

  // layer 2 commuted: stage[g] = sum_{v in g} Agg(h1)[v]; then (stage/n) @ W2 + b2
  k_aggpool128<<<gA, 256, 0, stream>>>(h1b, dinv, startv, cnt, colw, batch, stage, N);
  k_final<<<1, 256, 0, stream>>>(stage, firstIdx, W2, b2, outp, N);
}